// Round 1
// baseline (592.622 us; speedup 1.0000x reference)
//
#include <hip/hip_runtime.h>
#include <math.h>

// FrequencyAttention: B=4 S=1024 D=1024 H=16 M=64 HD=64, fp32 throughout.
// Only first M=64 frequencies survive the filter -> truncated DFT as GEMMs.
#define Bsz 4
#define Sdim 1024
#define Ddim 1024
#define Hn 16
#define Mf 64
#define HDd 64
#define D3 3072
#define BS 4096            // Bsz*Sdim

// ---------------- twiddle init: TWF[2f][s], TWI[s][2f], f<64, s<1024 ----------
__global__ void init_tw(float* __restrict__ TWF, float* __restrict__ TWI) {
    int idx = blockIdx.x * 256 + threadIdx.x;     // 65536 threads
    int f = idx >> 10, s = idx & 1023;
    float th = (float)((f * s) & 1023) * (6.283185307179586f / 1024.0f);
    float sn, c;
    sincosf(th, &sn, &c);
    TWF[(2 * f) * 1024 + s]     = c;
    TWF[(2 * f + 1) * 1024 + s] = sn;
    TWI[s * 128 + 2 * f]        = c;
    TWI[s * 128 + 2 * f + 1]    = sn;
}

// ---------------- NT GEMM: C[m,n] = sum_k A[m,k]*Bm[n,k] + bias[n] -----------
// 64x64 tile, BK=16, 256 threads, 4x4 micro-tile.
__global__ void gemm_nt(const float* __restrict__ A, const float* __restrict__ Bm,
                        const float* __restrict__ bias, float* __restrict__ C,
                        int N, int K) {
    __shared__ float As[16][68];
    __shared__ float Bs[16][68];
    int n0 = blockIdx.x * 64, m0 = blockIdx.y * 64;
    int tid = threadIdx.x;
    int tm = tid >> 4, tn = tid & 15;
    int lrow = tid >> 2, lc = (tid & 3) * 4;
    float acc[4][4] = {};
    for (int k0 = 0; k0 < K; k0 += 16) {
        float4 a = *(const float4*)&A[(size_t)(m0 + lrow) * K + k0 + lc];
        float4 b = *(const float4*)&Bm[(size_t)(n0 + lrow) * K + k0 + lc];
        As[lc + 0][lrow] = a.x; As[lc + 1][lrow] = a.y;
        As[lc + 2][lrow] = a.z; As[lc + 3][lrow] = a.w;
        Bs[lc + 0][lrow] = b.x; Bs[lc + 1][lrow] = b.y;
        Bs[lc + 2][lrow] = b.z; Bs[lc + 3][lrow] = b.w;
        __syncthreads();
#pragma unroll
        for (int kk = 0; kk < 16; kk++) {
            float av[4], bv[4];
            *(float4*)av = *(const float4*)&As[kk][tm * 4];
            *(float4*)bv = *(const float4*)&Bs[kk][tn * 4];
#pragma unroll
            for (int i = 0; i < 4; i++)
#pragma unroll
                for (int j = 0; j < 4; j++)
                    acc[i][j] += av[i] * bv[j];
        }
        __syncthreads();
    }
#pragma unroll
    for (int i = 0; i < 4; i++) {
        int row = m0 + tm * 4 + i;
#pragma unroll
        for (int j = 0; j < 4; j++) {
            int col = n0 + tn * 4 + j;
            C[(size_t)row * N + col] = acc[i][j] + bias[col];
        }
    }
}

// ---------------- shared 128x64 NN-GEMM body (A row-major, K-contig) ---------
__device__ __forceinline__ void gemm_128x64(const float* __restrict__ A, int lda,
                                            const float* __restrict__ Bsrc, int ldb,
                                            float* __restrict__ Cdst, int ldc, int K) {
    __shared__ float As[16][132];
    __shared__ float Bs[16][68];
    int tid = threadIdx.x;
    int tm = tid >> 4, tn = tid & 15;
    float acc[8][4] = {};
    for (int k0 = 0; k0 < K; k0 += 16) {
        {
            int row = tid >> 1, c8 = (tid & 1) * 8;
            const float* ap = A + (size_t)row * lda + k0 + c8;
            float4 a0 = *(const float4*)ap;
            float4 a1 = *(const float4*)(ap + 4);
            As[c8 + 0][row] = a0.x; As[c8 + 1][row] = a0.y;
            As[c8 + 2][row] = a0.z; As[c8 + 3][row] = a0.w;
            As[c8 + 4][row] = a1.x; As[c8 + 5][row] = a1.y;
            As[c8 + 6][row] = a1.z; As[c8 + 7][row] = a1.w;
            int brow = tid >> 4, bc = (tid & 15) * 4;
            float4 b = *(const float4*)&Bsrc[(size_t)(k0 + brow) * ldb + bc];
            *(float4*)&Bs[brow][bc] = b;
        }
        __syncthreads();
#pragma unroll
        for (int kk = 0; kk < 16; kk++) {
            float av[8], bv[4];
            *(float4*)&av[0] = *(const float4*)&As[kk][tm * 8];
            *(float4*)&av[4] = *(const float4*)&As[kk][tm * 8 + 4];
            *(float4*)bv = *(const float4*)&Bs[kk][tn * 4];
#pragma unroll
            for (int i = 0; i < 8; i++)
#pragma unroll
                for (int j = 0; j < 4; j++)
                    acc[i][j] += av[i] * bv[j];
        }
        __syncthreads();
    }
#pragma unroll
    for (int i = 0; i < 8; i++)
#pragma unroll
        for (int j = 0; j < 4; j++)
            Cdst[(size_t)(tm * 8 + i) * ldc + tn * 4 + j] = acc[i][j];
}

// fwd truncated DFT: per (b,h,tensor): C[128][64] = TWF[128x1024] * head[1024x64]
__global__ void fwd_dft(const float* __restrict__ TWF, const float* __restrict__ qkv,
                        float* __restrict__ QF) {
    int bh = blockIdx.x;          // b*16+h
    int tensor = blockIdx.y;      // 0=q,1=k,2=v
    int b = bh >> 4, h = bh & 15;
    const float* Bsrc = qkv + (size_t)b * Sdim * D3 + (size_t)tensor * Ddim + h * HDd;
    float* Cdst = QF + (size_t)tensor * 524288 + (size_t)bh * (128 * 64);
    gemm_128x64(TWF, 1024, Bsrc, D3, Cdst, 64, 1024);
}

// inverse truncated DFT: per (b,h): OUT_T[b, s, h*64+d] = TWI[1024x128] * OV[128x64]
__global__ void inv_dft(const float* __restrict__ TWI, const float* __restrict__ OV,
                        float* __restrict__ OUT_T) {
    int m0 = blockIdx.x * 128;    // s-tile
    int bh = blockIdx.y;
    int b = bh >> 4, h = bh & 15;
    gemm_128x64(TWI + (size_t)m0 * 128, 128,
                OV + (size_t)bh * 8192, 64,
                OUT_T + (size_t)b * Sdim * Ddim + (size_t)m0 * Ddim + h * HDd, Ddim, 128);
}

// scores + softmax (over S=1024 entries: 64 real scores + 960 zeros) + OV build
__global__ void score_ov(const float* __restrict__ QF, const float* __restrict__ KF,
                         const float* __restrict__ VF,
                         const float* __restrict__ fq, const float* __restrict__ fk,
                         const float* __restrict__ fv, float* __restrict__ OV) {
    int bh = blockIdx.x;
    int h = bh & 15;
    const float* qf = QF + (size_t)bh * 8192;
    const float* kf = KF + (size_t)bh * 8192;
    const float* vf = VF + (size_t)bh * 8192;
    const float* wq = fq + (size_t)h * 4096;
    const float* wk = fk + (size_t)h * 4096;
    const float* wv = fv + (size_t)h * 4096;
    __shared__ float red[256];
    __shared__ float attn[64];
    int tid = threadIdx.x;
    int f = tid & 63, dg = tid >> 6;
    float p = 0.f;
#pragma unroll
    for (int i = 0; i < 16; i++) {
        int d = dg * 16 + i;
        float w2 = wq[f * 64 + d] * wk[f * 64 + d];
        p += w2 * (qf[(2 * f) * 64 + d] * kf[(2 * f) * 64 + d] +
                   qf[(2 * f + 1) * 64 + d] * kf[(2 * f + 1) * 64 + d]);
    }
    red[tid] = p;
    __syncthreads();
    if (tid < 64) {
        float s = red[tid] + red[tid + 64] + red[tid + 128] + red[tid + 192];
        float mx = s;
        for (int m = 1; m < 64; m <<= 1) mx = fmaxf(mx, __shfl_xor(mx, m));
        mx = fmaxf(mx, 0.0f);                       // padded zeros join the max
        float e = expf(s - mx);
        float sum = e;
        for (int m = 1; m < 64; m <<= 1) sum += __shfl_xor(sum, m);
        sum += 960.0f * expf(-mx);                  // the S-M zero-score entries
        attn[tid] = e / sum;
    }
    __syncthreads();
    float* ovb = OV + (size_t)bh * 8192;
    for (int i = tid; i < 8192; i += 256) {
        int r = i >> 6, d = i & 63, ff = r >> 1;
        ovb[i] = attn[ff] * wv[ff * 64 + d] * vf[i];
    }
}

extern "C" void kernel_launch(void* const* d_in, const int* in_sizes, int n_in,
                              void* d_out, int out_size, void* d_ws, size_t ws_size,
                              hipStream_t stream) {
    const float* query = (const float*)d_in[0];
    const float* w_qkv = (const float*)d_in[1];
    const float* b_qkv = (const float*)d_in[2];
    const float* w_out = (const float*)d_in[3];
    const float* b_out = (const float*)d_in[4];
    const float* freq_q = (const float*)d_in[5];
    const float* freq_k = (const float*)d_in[6];
    const float* freq_v = (const float*)d_in[7];

    float* W = (float*)d_ws;
    float* qkv   = W;                         // 12,582,912 floats (48 MB)
    float* OUT_T = W;                         // aliases qkv (qkv dead after fwd_dft)
    float* QF    = W + (size_t)BS * D3;       // 524,288 floats each
    float* KF    = QF + 524288;
    float* VF    = KF + 524288;
    float* OV    = VF + 524288;
    float* TWF   = OV + 524288;               // 131,072
    float* TWI   = TWF + 131072;              // 131,072

    init_tw<<<256, 256, 0, stream>>>(TWF, TWI);
    // qkv = query @ w_qkv^T + b_qkv   [4096 x 3072]
    gemm_nt<<<dim3(48, 64), 256, 0, stream>>>(query, w_qkv, b_qkv, qkv, D3, Ddim);
    // truncated forward DFT of q,k,v heads
    fwd_dft<<<dim3(64, 3), 256, 0, stream>>>(TWF, qkv, QF);
    // scores -> softmax(1024-wide) -> OV = attn * wv * v_fft
    score_ov<<<64, 256, 0, stream>>>(QF, KF, VF, freq_q, freq_k, freq_v, OV);
    // inverse truncated DFT -> time domain [B,S,D]
    inv_dft<<<dim3(8, 64), 256, 0, stream>>>(TWI, OV, OUT_T);
    // final projection: d_out = OUT_T @ w_out^T + b_out   [4096 x 1024]
    gemm_nt<<<dim3(16, 64), 256, 0, stream>>>(OUT_T, w_out, b_out, (float*)d_out, Ddim, Ddim);
}

// Round 3
// 263.634 us; speedup vs baseline: 2.2479x; 2.2479x over previous
//
#include <hip/hip_runtime.h>
#include <math.h>

// FrequencyAttention: B=4 S=1024 D=1024 H=16 M=64 HD=64.
// All GEMMs on split-bf16 MFMA (hi/lo, 3-term). Scores/softmax stay fp32.

typedef __bf16 bf16x8 __attribute__((ext_vector_type(8)));
typedef float  f32x4  __attribute__((ext_vector_type(4)));

__device__ __forceinline__ unsigned short f2bf(float x) {
    unsigned u = __builtin_bit_cast(unsigned, x);
    u = (u + 0x7fffu + ((u >> 16) & 1u)) >> 16;   // RTN-even
    return (unsigned short)u;
}
__device__ __forceinline__ float bf2f(unsigned short h) {
    return __builtin_bit_cast(float, ((unsigned)h) << 16);
}
__device__ __forceinline__ void split2(float x, unsigned short& h, unsigned short& l) {
    h = f2bf(x);
    l = f2bf(x - bf2f(h));
}

__device__ __forceinline__ void gload16(const void* g, void* l) {
    __builtin_amdgcn_global_load_lds(
        (const __attribute__((address_space(1))) unsigned int*)g,
        (__attribute__((address_space(3))) unsigned int*)l,
        16, 0, 0);
}

// ---- twiddles: TWF[128][1024] (rows 2f=cos, 2f+1=sin), TWI[1024][128], hi/lo bf16
__global__ void init_tw2(unsigned short* __restrict__ TWFh, unsigned short* __restrict__ TWFl,
                         unsigned short* __restrict__ TWIh, unsigned short* __restrict__ TWIl) {
    int idx = blockIdx.x * 256 + threadIdx.x;   // 65536 = 64f x 1024s
    int f = idx >> 10, s = idx & 1023;
    float th = (float)((f * s) & 1023) * (6.283185307179586f / 1024.0f);
    float sn, c;
    sincosf(th, &sn, &c);
    unsigned short ch, cl, sh, sl;
    split2(c, ch, cl); split2(sn, sh, sl);
    TWFh[(2 * f) * 1024 + s] = ch;     TWFl[(2 * f) * 1024 + s] = cl;
    TWFh[(2 * f + 1) * 1024 + s] = sh; TWFl[(2 * f + 1) * 1024 + s] = sl;
    TWIh[s * 128 + 2 * f] = ch;        TWIl[s * 128 + 2 * f] = cl;
    TWIh[s * 128 + 2 * f + 1] = sh;    TWIl[s * 128 + 2 * f + 1] = sl;
}

// ---- split fp32 inputs (query, w_qkv, w_out) into hi/lo bf16 arrays
__global__ void split_all(const float* __restrict__ q, const float* __restrict__ wq,
                          const float* __restrict__ wo,
                          unsigned short* __restrict__ Qh, unsigned short* __restrict__ Ql,
                          unsigned short* __restrict__ Wh, unsigned short* __restrict__ Wl,
                          unsigned short* __restrict__ Uh, unsigned short* __restrict__ Ul) {
    long i = (long)blockIdx.x * 256 + threadIdx.x;      // float4 index, total 2097152
    const float* src; unsigned short *dh, *dl; long off;
    if (i < 1048576)            { src = q;  dh = Qh; dl = Ql; off = i; }
    else if (i < 1835008)       { src = wq; dh = Wh; dl = Wl; off = i - 1048576; }
    else                        { src = wo; dh = Uh; dl = Ul; off = i - 1835008; }
    float4 v = ((const float4*)src)[off];
    ushort4 hh, ll;
    split2(v.x, hh.x, ll.x); split2(v.y, hh.y, ll.y);
    split2(v.z, hh.z, ll.z); split2(v.w, hh.w, ll.w);
    ((ushort4*)dh)[off] = hh;
    ((ushort4*)dl)[off] = ll;
}

// ---- split-bf16 MFMA NT GEMM: C[m][n] = sum_k A[m][k]*B[n][k] (+bias)
// 128x128 tile, 4 waves, K-step 32. LDS in fragment order so global_load_lds
// is linear and ds_read_b128 is conflict-free.
template<bool BIAS_M, bool BIAS_N, bool SPLIT>
__global__ __launch_bounds__(256, 2) void mfma_gemm(
    const unsigned short* __restrict__ Ah, const unsigned short* __restrict__ Al, int lda,
    const unsigned short* __restrict__ Bh, const unsigned short* __restrict__ Bl, int ldb, long bsB,
    float* __restrict__ Cf, unsigned short* __restrict__ Ch, unsigned short* __restrict__ Cl,
    int ldc, long bsC, const float* __restrict__ bias, int K)
{
    __shared__ unsigned short smem[16384];   // Ah|Al|Bh|Bl tiles, 8KB each
    const int tid = threadIdx.x, lane = tid & 63, w = tid >> 6;
    const int wm = w >> 1, wn = w & 1;
    const int m0 = blockIdx.y * 128, n0 = blockIdx.x * 128;
    const int la = lane & 15, kg = lane >> 4;

    const unsigned short* Bhb = Bh + (long)blockIdx.z * bsB;
    const unsigned short* Blb = Bl + (long)blockIdx.z * bsB;

    const unsigned short* sA0[2]; const unsigned short* sA1[2];
    const unsigned short* sB0[2]; const unsigned short* sB1[2];
#pragma unroll
    for (int rr = 0; rr < 2; rr++) {
        int rb = w * 2 + rr;
        sA0[rr] = Ah  + (size_t)(m0 + rb * 16 + la) * lda + kg * 8;
        sA1[rr] = Al  + (size_t)(m0 + rb * 16 + la) * lda + kg * 8;
        sB0[rr] = Bhb + (size_t)(n0 + rb * 16 + la) * ldb + kg * 8;
        sB1[rr] = Blb + (size_t)(n0 + rb * 16 + la) * ldb + kg * 8;
    }

    f32x4 acc[4][4] = {};
    const int ktiles = K >> 5;
    for (int kt = 0; kt < ktiles; ++kt) {
#pragma unroll
        for (int rr = 0; rr < 2; rr++) {
            int rb = w * 2 + rr;
            gload16(sA0[rr], &smem[rb * 512]);
            gload16(sA1[rr], &smem[4096 + rb * 512]);
            gload16(sB0[rr], &smem[8192 + rb * 512]);
            gload16(sB1[rr], &smem[12288 + rb * 512]);
            sA0[rr] += 32; sA1[rr] += 32; sB0[rr] += 32; sB1[rr] += 32;
        }
        __syncthreads();
        bf16x8 fah[4], fal[4];
#pragma unroll
        for (int i = 0; i < 4; i++) {
            fah[i] = *reinterpret_cast<const bf16x8*>(&smem[(wm * 4 + i) * 512 + lane * 8]);
            fal[i] = *reinterpret_cast<const bf16x8*>(&smem[4096 + (wm * 4 + i) * 512 + lane * 8]);
        }
#pragma unroll
        for (int j = 0; j < 4; j++) {
            bf16x8 fbh = *reinterpret_cast<const bf16x8*>(&smem[8192 + (wn * 4 + j) * 512 + lane * 8]);
            bf16x8 fbl = *reinterpret_cast<const bf16x8*>(&smem[12288 + (wn * 4 + j) * 512 + lane * 8]);
#pragma unroll
            for (int i = 0; i < 4; i++) {
                acc[i][j] = __builtin_amdgcn_mfma_f32_16x16x32_bf16(fah[i], fbh, acc[i][j], 0, 0, 0);
                acc[i][j] = __builtin_amdgcn_mfma_f32_16x16x32_bf16(fal[i], fbh, acc[i][j], 0, 0, 0);
                acc[i][j] = __builtin_amdgcn_mfma_f32_16x16x32_bf16(fah[i], fbl, acc[i][j], 0, 0, 0);
            }
        }
        __syncthreads();
    }

    // epilogue: C/D layout col=lane&15, row=(lane>>4)*4+r
    const int r0 = (lane >> 4) * 4, cl = lane & 15;
    float* Cfb = Cf ? Cf + (long)blockIdx.z * bsC : nullptr;
    unsigned short* Chb = Ch ? Ch + (long)blockIdx.z * bsC : nullptr;
    unsigned short* Clb = Cl ? Cl + (long)blockIdx.z * bsC : nullptr;
#pragma unroll
    for (int i = 0; i < 4; i++) {
#pragma unroll
        for (int j = 0; j < 4; j++) {
            int gr0 = m0 + wm * 64 + i * 16 + r0;
            int gc  = n0 + wn * 64 + j * 16 + cl;
            float bn = BIAS_N ? bias[gc] : 0.f;
#pragma unroll
            for (int r = 0; r < 4; r++) {
                int gr = gr0 + r;
                float v = acc[i][j][r] + bn + (BIAS_M ? bias[gr] : 0.f);
                size_t o = (size_t)gr * ldc + gc;
                if (SPLIT) {
                    unsigned short hh, ll; split2(v, hh, ll);
                    Chb[o] = hh; Clb[o] = ll;
                } else {
                    Cfb[o] = v;
                }
            }
        }
    }
}

// ---- scores (fp32) + 1024-wide softmax + OVT = attn*wv*vf, written [b][col][f2] hi/lo
__global__ void score_ov2(const float* __restrict__ QF,
                          const float* __restrict__ fq, const float* __restrict__ fk,
                          const float* __restrict__ fv,
                          unsigned short* __restrict__ OVTh, unsigned short* __restrict__ OVTl) {
    int bh = blockIdx.x, b = bh >> 4, h = bh & 15;
    const float* QFb = QF + (size_t)b * 393216;     // [128 f2][3072]
    const float* wq = fq + (size_t)h * 4096;
    const float* wk = fk + (size_t)h * 4096;
    const float* wv = fv + (size_t)h * 4096;
    __shared__ float red[256];
    __shared__ float attn[64];
    int tid = threadIdx.x;
    int f = tid & 63, dg = tid >> 6;
    int cq = h * 64;
    float p = 0.f;
#pragma unroll
    for (int i = 0; i < 16; i++) {
        int d = dg * 16 + i;
        float w2 = wq[f * 64 + d] * wk[f * 64 + d];
        p += w2 * (QFb[(2 * f) * 3072 + cq + d]     * QFb[(2 * f) * 3072 + 1024 + cq + d]
                 + QFb[(2 * f + 1) * 3072 + cq + d] * QFb[(2 * f + 1) * 3072 + 1024 + cq + d]);
    }
    red[tid] = p;
    __syncthreads();
    if (tid < 64) {
        float s = red[tid] + red[tid + 64] + red[tid + 128] + red[tid + 192];
        float mx = s;
        for (int m = 1; m < 64; m <<= 1) mx = fmaxf(mx, __shfl_xor(mx, m));
        mx = fmaxf(mx, 0.0f);                   // padded zero scores join the max
        float e = expf(s - mx);
        float sum = e;
        for (int m = 1; m < 64; m <<= 1) sum += __shfl_xor(sum, m);
        sum += 960.0f * expf(-mx);              // the S-M zero-score entries
        attn[tid] = e / sum;
    }
    __syncthreads();
    for (int i = tid; i < 8192; i += 256) {
        int f2 = i & 127, dcol = i >> 7;
        float val = attn[f2 >> 1] * wv[(f2 >> 1) * 64 + dcol]
                  * QFb[(size_t)f2 * 3072 + 2048 + cq + dcol];
        unsigned short hh, ll; split2(val, hh, ll);
        size_t o = (size_t)b * 131072 + (size_t)(cq + dcol) * 128 + f2;
        OVTh[o] = hh; OVTl[o] = ll;
    }
}

extern "C" void kernel_launch(void* const* d_in, const int* in_sizes, int n_in,
                              void* d_out, int out_size, void* d_ws, size_t ws_size,
                              hipStream_t stream) {
    const float* query  = (const float*)d_in[0];
    const float* w_qkv  = (const float*)d_in[1];
    const float* b_qkv  = (const float*)d_in[2];
    const float* w_out  = (const float*)d_in[3];
    const float* b_out  = (const float*)d_in[4];
    const float* freq_q = (const float*)d_in[5];
    const float* freq_k = (const float*)d_in[6];
    const float* freq_v = (const float*)d_in[7];

    char* W = (char*)d_ws;
    unsigned short* qkvTh = (unsigned short*)(W);                 // [3072][4096] 25.2MB
    unsigned short* qkvTl = (unsigned short*)(W + 25165824);      // 25.2MB
    unsigned short* Qh    = (unsigned short*)(W + 50331648);      // [4096][1024] 8.4MB
    unsigned short* Ql    = (unsigned short*)(W + 58720256);      // 8.4MB
    unsigned short* Wh    = (unsigned short*)(W + 67108864);      // [3072][1024] 6.3MB
    unsigned short* Wl    = (unsigned short*)(W + 73400320);      // 6.3MB
    unsigned short* Uh    = (unsigned short*)(W + 79691776);      // [1024][1024] 2.1MB
    unsigned short* Ul    = (unsigned short*)(W + 81788928);      // 2.1MB
    unsigned short* TWFh  = (unsigned short*)(W + 83886080);      // [128][1024]
    unsigned short* TWFl  = (unsigned short*)(W + 84148224);
    unsigned short* TWIh  = (unsigned short*)(W + 84410368);      // [1024][128]
    unsigned short* TWIl  = (unsigned short*)(W + 84672512);      // end 84934656 B
    // liveness-safe aliases:
    float* QF            = (float*)Wh;          // [4][128][3072] fp32, after GEMM1
    unsigned short* OVTh = Wl;                  // [4][1024][128], after GEMM2
    unsigned short* OVTl = Wl + 524288;
    unsigned short* OUTh = Qh;                  // [4096][1024], after GEMM1
    unsigned short* OUTl = Ql;

    init_tw2<<<256, 256, 0, stream>>>(TWFh, TWFl, TWIh, TWIl);
    split_all<<<8192, 256, 0, stream>>>(query, w_qkv, w_out, Qh, Ql, Wh, Wl, Uh, Ul);

    // GEMM1: qkvT[c][bs] = sum_k w_qkv[c][k]*query[bs][k] + b_qkv[c]  -> split bf16
    mfma_gemm<true, false, true><<<dim3(32, 24, 1), 256, 0, stream>>>(
        Wh, Wl, 1024, Qh, Ql, 1024, 0,
        nullptr, qkvTh, qkvTl, 4096, 0, b_qkv, 1024);

    // GEMM2 (fwd DFT, per b): QF[b][f2][col] = sum_s TWF[f2][s]*qkvT[col][b*1024+s]
    mfma_gemm<false, false, false><<<dim3(24, 1, 4), 256, 0, stream>>>(
        TWFh, TWFl, 1024, qkvTh, qkvTl, 4096, 1024,
        QF, nullptr, nullptr, 3072, 393216, nullptr, 1024);

    // scores -> softmax(1024-wide) -> OVT[b][col][f2] split bf16
    score_ov2<<<64, 256, 0, stream>>>(QF, freq_q, freq_k, freq_v, OVTh, OVTl);

    // GEMM3 (inv DFT, per b): OUT[b*1024+s][col] = sum_f2 TWI[s][f2]*OVT[b][col][f2]
    mfma_gemm<false, false, true><<<dim3(8, 8, 4), 256, 0, stream>>>(
        TWIh, TWIl, 128, OVTh, OVTl, 128, 131072,
        nullptr, OUTh, OUTl, 1024, 1048576, nullptr, 128);

    // GEMM4: d_out[bs][n] = sum_k OUT[bs][k]*w_out[n][k] + b_out[n]
    mfma_gemm<false, true, false><<<dim3(8, 32, 1), 256, 0, stream>>>(
        OUTh, OUTl, 1024, Uh, Ul, 1024, 0,
        (float*)d_out, nullptr, nullptr, 1024, 0, b_out, 1024);
}

// Round 5
// 207.267 us; speedup vs baseline: 2.8592x; 1.2719x over previous
//
#include <hip/hip_runtime.h>
#include <math.h>

// FrequencyAttention restructured: never materialize time-domain qkv.
// QF = (TWF. qT) . W^T ;  d_out = TWI . (U . OVW^T)^T + b_out.
// All GEMMs split-bf16 MFMA (hi/lo, 3-term). Scores/softmax fp32.

typedef __bf16 bf16x8 __attribute__((ext_vector_type(8)));
typedef float  f32x4  __attribute__((ext_vector_type(4)));

__device__ __forceinline__ unsigned short f2bf(float x) {
    unsigned u = __builtin_bit_cast(unsigned, x);
    u = (u + 0x7fffu + ((u >> 16) & 1u)) >> 16;   // RTN-even
    return (unsigned short)u;
}
__device__ __forceinline__ float bf2f(unsigned short h) {
    return __builtin_bit_cast(float, ((unsigned)h) << 16);
}
__device__ __forceinline__ void split2(float x, unsigned short& h, unsigned short& l) {
    h = f2bf(x);
    l = f2bf(x - bf2f(h));
}

__device__ __forceinline__ void gload16(const void* g, void* l) {
    __builtin_amdgcn_global_load_lds(
        (const __attribute__((address_space(1))) unsigned int*)g,
        (__attribute__((address_space(3))) unsigned int*)l,
        16, 0, 0);
}

// ---- twiddles: TWF[128][1024] (rows 2f=cos, 2f+1=sin), TWI[1024][128], hi/lo
__global__ void init_tw2(unsigned short* __restrict__ TWFh, unsigned short* __restrict__ TWFl,
                         unsigned short* __restrict__ TWIh, unsigned short* __restrict__ TWIl) {
    int idx = blockIdx.x * 256 + threadIdx.x;   // 65536 = 64f x 1024s
    int f = idx >> 10, s = idx & 1023;
    float th = (float)((f * s) & 1023) * (6.283185307179586f / 1024.0f);
    float sn, c;
    sincosf(th, &sn, &c);
    unsigned short ch, cl, sh, sl;
    split2(c, ch, cl); split2(sn, sh, sl);
    TWFh[(2 * f) * 1024 + s] = ch;     TWFl[(2 * f) * 1024 + s] = cl;
    TWFh[(2 * f + 1) * 1024 + s] = sh; TWFl[(2 * f + 1) * 1024 + s] = sl;
    TWIh[s * 128 + 2 * f] = ch;        TWIl[s * 128 + 2 * f] = cl;
    TWIh[s * 128 + 2 * f + 1] = sh;    TWIl[s * 128 + 2 * f + 1] = sl;
}

// ---- split w_qkv, w_out into hi/lo bf16
__global__ void split_wu(const float* __restrict__ wq, const float* __restrict__ wo,
                         unsigned short* __restrict__ Wh, unsigned short* __restrict__ Wl,
                         unsigned short* __restrict__ Uh, unsigned short* __restrict__ Ul) {
    long i = (long)blockIdx.x * 256 + threadIdx.x;   // float4 idx, total 1048576
    const float* src; unsigned short *dh, *dl; long off;
    if (i < 786432) { src = wq; dh = Wh; dl = Wl; off = i; }
    else            { src = wo; dh = Uh; dl = Ul; off = i - 786432; }
    float4 v = ((const float4*)src)[off];
    ushort4 hh, ll;
    split2(v.x, hh.x, ll.x); split2(v.y, hh.y, ll.y);
    split2(v.z, hh.z, ll.z); split2(v.w, hh.w, ll.w);
    ((ushort4*)dh)[off] = hh;
    ((ushort4*)dl)[off] = ll;
}

// ---- transpose+split query: [b][s][k] fp32 -> qT[b][k][s] hi/lo bf16
__global__ void transpose_split_q(const float* __restrict__ q,
                                  unsigned short* __restrict__ qTh,
                                  unsigned short* __restrict__ qTl) {
    __shared__ float T[64][65];
    int b = blockIdx.z;
    int k0 = blockIdx.x * 64, s0 = blockIdx.y * 64;
    const float* src = q + ((size_t)b * 1024 + s0) * 1024 + k0;
    int tr = threadIdx.x >> 4, tc4 = (threadIdx.x & 15) * 4;
#pragma unroll
    for (int rs = 0; rs < 4; rs++) {
        int r = rs * 16 + tr;                          // s-local
        float4 v = *(const float4*)&src[(size_t)r * 1024 + tc4];
        T[tc4 + 0][r] = v.x; T[tc4 + 1][r] = v.y;
        T[tc4 + 2][r] = v.z; T[tc4 + 3][r] = v.w;
    }
    __syncthreads();
    unsigned short* dh = qTh + ((size_t)b * 1024 + k0) * 1024 + s0;
    unsigned short* dl = qTl + ((size_t)b * 1024 + k0) * 1024 + s0;
#pragma unroll
    for (int rs = 0; rs < 4; rs++) {
        int kk = rs * 16 + tr;                         // k-local
        ushort4 hh, ll;
        split2(T[kk][tc4 + 0], hh.x, ll.x);
        split2(T[kk][tc4 + 1], hh.y, ll.y);
        split2(T[kk][tc4 + 2], hh.z, ll.z);
        split2(T[kk][tc4 + 3], hh.w, ll.w);
        *(ushort4*)&dh[(size_t)kk * 1024 + tc4] = hh;
        *(ushort4*)&dl[(size_t)kk * 1024 + tc4] = ll;
    }
}

// ---- split-bf16 MFMA NT GEMM: C[m][n] = sum_k A[m][k]*B[n][k] (+bias modes)
// BMODE: 0 none, 1 col-bias b[n], 2 DC-row bias (+1024*b[n] at row 0)
template<int BMODE, bool SPLIT>
__global__ __launch_bounds__(256, 2) void mfma_gemm(
    const unsigned short* __restrict__ Ah, const unsigned short* __restrict__ Al,
    int lda, long bsA,
    const unsigned short* __restrict__ Bh, const unsigned short* __restrict__ Bl,
    int ldb, long bsB,
    float* __restrict__ Cf, unsigned short* __restrict__ Ch, unsigned short* __restrict__ Cl,
    int ldc, long bsC, const float* __restrict__ bias, int K)
{
    __shared__ unsigned short smem[16384];   // Ah|Al|Bh|Bl tiles, 8KB each
    const int tid = threadIdx.x, lane = tid & 63, w = tid >> 6;
    const int wm = w >> 1, wn = w & 1;
    const int m0 = blockIdx.y * 128, n0 = blockIdx.x * 128;
    const int la = lane & 15, kg = lane >> 4;

    const unsigned short* Ahb = Ah + (long)blockIdx.z * bsA;
    const unsigned short* Alb = Al + (long)blockIdx.z * bsA;
    const unsigned short* Bhb = Bh + (long)blockIdx.z * bsB;
    const unsigned short* Blb = Bl + (long)blockIdx.z * bsB;

    const unsigned short* sA0[2]; const unsigned short* sA1[2];
    const unsigned short* sB0[2]; const unsigned short* sB1[2];
#pragma unroll
    for (int rr = 0; rr < 2; rr++) {
        int rb = w * 2 + rr;
        sA0[rr] = Ahb + (size_t)(m0 + rb * 16 + la) * lda + kg * 8;
        sA1[rr] = Alb + (size_t)(m0 + rb * 16 + la) * lda + kg * 8;
        sB0[rr] = Bhb + (size_t)(n0 + rb * 16 + la) * ldb + kg * 8;
        sB1[rr] = Blb + (size_t)(n0 + rb * 16 + la) * ldb + kg * 8;
    }

    f32x4 acc[4][4] = {};
    const int ktiles = K >> 5;
    for (int kt = 0; kt < ktiles; ++kt) {
#pragma unroll
        for (int rr = 0; rr < 2; rr++) {
            int rb = w * 2 + rr;
            gload16(sA0[rr], &smem[rb * 512]);
            gload16(sA1[rr], &smem[4096 + rb * 512]);
            gload16(sB0[rr], &smem[8192 + rb * 512]);
            gload16(sB1[rr], &smem[12288 + rb * 512]);
            sA0[rr] += 32; sA1[rr] += 32; sB0[rr] += 32; sB1[rr] += 32;
        }
        __syncthreads();
        bf16x8 fah[4], fal[4];
#pragma unroll
        for (int i = 0; i < 4; i++) {
            fah[i] = *reinterpret_cast<const bf16x8*>(&smem[(wm * 4 + i) * 512 + lane * 8]);
            fal[i] = *reinterpret_cast<const bf16x8*>(&smem[4096 + (wm * 4 + i) * 512 + lane * 8]);
        }
#pragma unroll
        for (int j = 0; j < 4; j++) {
            bf16x8 fbh = *reinterpret_cast<const bf16x8*>(&smem[8192 + (wn * 4 + j) * 512 + lane * 8]);
            bf16x8 fbl = *reinterpret_cast<const bf16x8*>(&smem[12288 + (wn * 4 + j) * 512 + lane * 8]);
#pragma unroll
            for (int i = 0; i < 4; i++) {
                acc[i][j] = __builtin_amdgcn_mfma_f32_16x16x32_bf16(fah[i], fbh, acc[i][j], 0, 0, 0);
                acc[i][j] = __builtin_amdgcn_mfma_f32_16x16x32_bf16(fal[i], fbh, acc[i][j], 0, 0, 0);
                acc[i][j] = __builtin_amdgcn_mfma_f32_16x16x32_bf16(fah[i], fbl, acc[i][j], 0, 0, 0);
            }
        }
        __syncthreads();
    }

    // epilogue: C/D layout col=lane&15, row=(lane>>4)*4+r
    const int r0 = (lane >> 4) * 4, cl = lane & 15;
    float* Cfb = Cf ? Cf + (long)blockIdx.z * bsC : nullptr;
    unsigned short* Chb = Ch ? Ch + (long)blockIdx.z * bsC : nullptr;
    unsigned short* Clb = Cl ? Cl + (long)blockIdx.z * bsC : nullptr;
#pragma unroll
    for (int i = 0; i < 4; i++) {
#pragma unroll
        for (int j = 0; j < 4; j++) {
            int gr0 = m0 + wm * 64 + i * 16 + r0;
            int gc  = n0 + wn * 64 + j * 16 + cl;
            float bn = (BMODE == 1) ? bias[gc] : 0.f;
#pragma unroll
            for (int r = 0; r < 4; r++) {
                int gr = gr0 + r;
                float v = acc[i][j][r] + bn;
                if (BMODE == 2 && gr == 0) v += 1024.0f * bias[gc];
                size_t o = (size_t)gr * ldc + gc;
                if (SPLIT) {
                    unsigned short hh, ll; split2(v, hh, ll);
                    Chb[o] = hh; Clb[o] = ll;
                } else {
                    Cfb[o] = v;
                }
            }
        }
    }
}

// ---- scores (fp32) + 1024-wide softmax + OVW[b][f2][ch] = attn*wv*vf, hi/lo
__global__ void score_ov3(const float* __restrict__ QF,
                          const float* __restrict__ fq, const float* __restrict__ fk,
                          const float* __restrict__ fv,
                          unsigned short* __restrict__ OVWh, unsigned short* __restrict__ OVWl) {
    int bh = blockIdx.x, b = bh >> 4, h = bh & 15;
    const float* QFb = QF + (size_t)b * 393216;     // [128 f2][3072 ch]
    const float* wq = fq + (size_t)h * 4096;
    const float* wk = fk + (size_t)h * 4096;
    const float* wv = fv + (size_t)h * 4096;
    __shared__ float red[256];
    __shared__ float attn[64];
    int tid = threadIdx.x;
    int f = tid & 63, dg = tid >> 6;
    int cq = h * 64;
    float p = 0.f;
#pragma unroll
    for (int i = 0; i < 16; i++) {
        int d = dg * 16 + i;
        float w2 = wq[f * 64 + d] * wk[f * 64 + d];
        p += w2 * (QFb[(2 * f) * 3072 + cq + d]     * QFb[(2 * f) * 3072 + 1024 + cq + d]
                 + QFb[(2 * f + 1) * 3072 + cq + d] * QFb[(2 * f + 1) * 3072 + 1024 + cq + d]);
    }
    red[tid] = p;
    __syncthreads();
    if (tid < 64) {
        float s = red[tid] + red[tid + 64] + red[tid + 128] + red[tid + 192];
        float mx = s;
        for (int m = 1; m < 64; m <<= 1) mx = fmaxf(mx, __shfl_xor(mx, m));
        mx = fmaxf(mx, 0.0f);                   // padded zero scores join the max
        float e = expf(s - mx);
        float sum = e;
        for (int m = 1; m < 64; m <<= 1) sum += __shfl_xor(sum, m);
        sum += 960.0f * expf(-mx);              // the S-M zero-score entries
        attn[tid] = e / sum;
    }
    __syncthreads();
    for (int i = tid; i < 8192; i += 256) {
        int f2 = i >> 6, d = i & 63;
        float val = attn[f2 >> 1] * wv[(f2 >> 1) * 64 + d]
                  * QFb[(size_t)f2 * 3072 + 2048 + cq + d];
        unsigned short hh, ll; split2(val, hh, ll);
        size_t o = (size_t)b * 131072 + (size_t)f2 * 1024 + cq + d;
        OVWh[o] = hh; OVWl[o] = ll;
    }
}

extern "C" void kernel_launch(void* const* d_in, const int* in_sizes, int n_in,
                              void* d_out, int out_size, void* d_ws, size_t ws_size,
                              hipStream_t stream) {
    const float* query  = (const float*)d_in[0];
    const float* w_qkv  = (const float*)d_in[1];
    const float* b_qkv  = (const float*)d_in[2];
    const float* w_out  = (const float*)d_in[3];
    const float* b_out  = (const float*)d_in[4];
    const float* freq_q = (const float*)d_in[5];
    const float* freq_k = (const float*)d_in[6];
    const float* freq_v = (const float*)d_in[7];

    char* W = (char*)d_ws;
    unsigned short* qTh  = (unsigned short*)(W);                  // [4][1024][1024] 8.39MB
    unsigned short* qTl  = (unsigned short*)(W + 8388608);
    unsigned short* Wh   = (unsigned short*)(W + 16777216);       // [3072][1024] 6.29MB
    unsigned short* Wl   = (unsigned short*)(W + 23068672);
    unsigned short* Uh   = (unsigned short*)(W + 29360128);       // [1024][1024] 2.1MB
    unsigned short* Ul   = (unsigned short*)(W + 31457280);
    unsigned short* TWFh = (unsigned short*)(W + 33554432);       // [128][1024]
    unsigned short* TWFl = (unsigned short*)(W + 33816576);
    unsigned short* TWIh = (unsigned short*)(W + 34078720);       // [1024][128]
    unsigned short* TWIl = (unsigned short*)(W + 34340864);
    unsigned short* TWQh = (unsigned short*)(W + 34603008);       // [4][128][1024] 1.05MB
    unsigned short* TWQl = (unsigned short*)(W + 35651584);
    float*          QF   = (float*)        (W + 36700160);        // [4][128][3072] fp32 6.29MB
    unsigned short* OVWh = (unsigned short*)(W + 42991616);       // [4][128][1024]
    unsigned short* OVWl = (unsigned short*)(W + 44040192);
    unsigned short* POVh = (unsigned short*)(W + 45088768);       // [4][1024][128]
    unsigned short* POVl = (unsigned short*)(W + 46137344);       // end 47185920 B

    init_tw2<<<256, 256, 0, stream>>>(TWFh, TWFl, TWIh, TWIl);
    split_wu<<<4096, 256, 0, stream>>>(w_qkv, w_out, Wh, Wl, Uh, Ul);
    transpose_split_q<<<dim3(16, 16, 4), 256, 0, stream>>>(query, qTh, qTl);

    // TWQ[b][f2][k] = sum_s TWF[f2][s] * qT[b][k][s]          (split out)
    mfma_gemm<0, true><<<dim3(8, 1, 4), 256, 0, stream>>>(
        TWFh, TWFl, 1024, 0, qTh, qTl, 1024, 1048576,
        nullptr, TWQh, TWQl, 1024, 131072, nullptr, 1024);

    // QF[b][f2][c] = sum_k TWQ[b][f2][k] * w_qkv[c][k]  (+1024*b_qkv at DC row)
    mfma_gemm<2, false><<<dim3(24, 1, 4), 256, 0, stream>>>(
        TWQh, TWQl, 1024, 131072, Wh, Wl, 1024, 0,
        QF, nullptr, nullptr, 3072, 393216, b_qkv, 1024);

    // scores -> softmax(1024-wide) -> OVW[b][f2][ch] split
    score_ov3<<<64, 256, 0, stream>>>(QF, freq_q, freq_k, freq_v, OVWh, OVWl);

    // POV[b][n][f2] = sum_ch w_out[n][ch] * OVW[b][f2][ch]    (split out)
    mfma_gemm<0, true><<<dim3(1, 8, 4), 256, 0, stream>>>(
        Uh, Ul, 1024, 0, OVWh, OVWl, 1024, 131072,
        nullptr, POVh, POVl, 128, 131072, nullptr, 1024);

    // d_out[b][s][n] = sum_f2 TWI[s][f2] * POV[b][n][f2] + b_out[n]
    mfma_gemm<1, false><<<dim3(8, 8, 4), 256, 0, stream>>>(
        TWIh, TWIl, 128, 0, POVh, POVl, 128, 131072,
        (float*)d_out, nullptr, nullptr, 1024, 1048576, b_out, 128);
}

// Round 9
// 100.182 us; speedup vs baseline: 5.9154x; 2.0689x over previous
//
#include <hip/hip_runtime.h>
#include <math.h>

// FrequencyAttention: QF = (TWF.qT).W^T ; d_out = TWI.(U.OVW^T)^T + b_out.
// Split-bf16 MFMA (hi/lo, 3-term) on 64x64 tiles; split-K=4 + fp32 reduce for
// the small-grid GEMMs (deterministic, no atomics). Scores/softmax fp32.

typedef __bf16 bf16x8 __attribute__((ext_vector_type(8)));
typedef float  f32x4  __attribute__((ext_vector_type(4)));

__device__ __forceinline__ unsigned short f2bf(float x) {
    unsigned u = __builtin_bit_cast(unsigned, x);
    u = (u + 0x7fffu + ((u >> 16) & 1u)) >> 16;   // RTN-even
    return (unsigned short)u;
}
__device__ __forceinline__ float bf2f(unsigned short h) {
    return __builtin_bit_cast(float, ((unsigned)h) << 16);
}
__device__ __forceinline__ void split2(float x, unsigned short& h, unsigned short& l) {
    h = f2bf(x);
    l = f2bf(x - bf2f(h));
}

__device__ __forceinline__ void gload16(const void* g, void* l) {
    __builtin_amdgcn_global_load_lds(
        (const __attribute__((address_space(1))) unsigned int*)g,
        (__attribute__((address_space(3))) unsigned int*)l,
        16, 0, 0);
}

// ---- fused prep: twiddles + weight split + query transpose/split ------------
__global__ __launch_bounds__(256) void prep(
    const float* __restrict__ q, const float* __restrict__ wq, const float* __restrict__ wo,
    unsigned short* __restrict__ qTh, unsigned short* __restrict__ qTl,
    unsigned short* __restrict__ Wh, unsigned short* __restrict__ Wl,
    unsigned short* __restrict__ Uh, unsigned short* __restrict__ Ul,
    unsigned short* __restrict__ TWFh, unsigned short* __restrict__ TWFl,
    unsigned short* __restrict__ TWIh, unsigned short* __restrict__ TWIl)
{
    __shared__ float T[64][65];
    int bid = blockIdx.x, tid = threadIdx.x;
    if (bid < 256) {                       // twiddles: 65536 = 64f x 1024s
        int idx = bid * 256 + tid;
        int f = idx >> 10, s = idx & 1023;
        float th = (float)((f * s) & 1023) * (6.283185307179586f / 1024.0f);
        float sn, c;
        sincosf(th, &sn, &c);
        unsigned short ch, cl, sh, sl;
        split2(c, ch, cl); split2(sn, sh, sl);
        TWFh[(2 * f) * 1024 + s] = ch;     TWFl[(2 * f) * 1024 + s] = cl;
        TWFh[(2 * f + 1) * 1024 + s] = sh; TWFl[(2 * f + 1) * 1024 + s] = sl;
        TWIh[s * 128 + 2 * f] = ch;        TWIl[s * 128 + 2 * f] = cl;
        TWIh[s * 128 + 2 * f + 1] = sh;    TWIl[s * 128 + 2 * f + 1] = sl;
    } else if (bid < 4352) {               // split w_qkv, w_out (float4 idx)
        long i = (long)(bid - 256) * 256 + tid;
        const float* src; unsigned short *dh, *dl; long off;
        if (i < 786432) { src = wq; dh = Wh; dl = Wl; off = i; }
        else            { src = wo; dh = Uh; dl = Ul; off = i - 786432; }
        float4 v = ((const float4*)src)[off];
        ushort4 hh, ll;
        split2(v.x, hh.x, ll.x); split2(v.y, hh.y, ll.y);
        split2(v.z, hh.z, ll.z); split2(v.w, hh.w, ll.w);
        ((ushort4*)dh)[off] = hh;
        ((ushort4*)dl)[off] = ll;
    } else {                               // transpose+split query
        int t = bid - 4352;                // 1024 blocks
        int k0 = (t & 15) * 64, s0 = ((t >> 4) & 15) * 64, b = t >> 8;
        const float* src = q + ((size_t)b * 1024 + s0) * 1024 + k0;
        int tr = tid >> 4, tc4 = (tid & 15) * 4;
#pragma unroll
        for (int rs = 0; rs < 4; rs++) {
            int r = rs * 16 + tr;
            float4 v = *(const float4*)&src[(size_t)r * 1024 + tc4];
            T[tc4 + 0][r] = v.x; T[tc4 + 1][r] = v.y;
            T[tc4 + 2][r] = v.z; T[tc4 + 3][r] = v.w;
        }
        __syncthreads();
        unsigned short* dh = qTh + ((size_t)b * 1024 + k0) * 1024 + s0;
        unsigned short* dl = qTl + ((size_t)b * 1024 + k0) * 1024 + s0;
#pragma unroll
        for (int rs = 0; rs < 4; rs++) {
            int kk = rs * 16 + tr;
            ushort4 hh, ll;
            split2(T[kk][tc4 + 0], hh.x, ll.x);
            split2(T[kk][tc4 + 1], hh.y, ll.y);
            split2(T[kk][tc4 + 2], hh.z, ll.z);
            split2(T[kk][tc4 + 3], hh.w, ll.w);
            *(ushort4*)&dh[(size_t)kk * 1024 + tc4] = hh;
            *(ushort4*)&dl[(size_t)kk * 1024 + tc4] = ll;
        }
    }
}

// ---- 64x64-tile split-bf16 MFMA NT GEMM, optional split-K partial output ----
// C[m][n] = sum_k A[m][k]*B[n][k]. KS>1: write fp32 partial P[z][M][N].
// BMODE: 0 none, 1 col-bias b[n], 2 DC-row bias (+1024*b[n] where (row&127)==0)
template<int KS, int BMODE, bool SPLIT>
__global__ __launch_bounds__(256, 4) void mfma64(
    const unsigned short* __restrict__ Ah, const unsigned short* __restrict__ Al,
    int lda, long bsA,
    const unsigned short* __restrict__ Bh, const unsigned short* __restrict__ Bl,
    int ldb, long bsB,
    float* __restrict__ Cf, unsigned short* __restrict__ Ch, unsigned short* __restrict__ Cl,
    int ldc, long bsC,
    float* __restrict__ Pf, const float* __restrict__ bias, int K)
{
    __shared__ unsigned short smem[8192];     // Ah|Al|Bh|Bl 64x32 tiles, 4KB each
    const int tid = threadIdx.x, lane = tid & 63, w = tid >> 6;
    const int wm = w >> 1, wn = w & 1;
    const int m0 = blockIdx.y * 64, n0 = blockIdx.x * 64;
    const int la = lane & 15, kg = lane >> 4;
    int bz, ks;
    if constexpr (KS > 1) { bz = blockIdx.z / KS; ks = blockIdx.z % KS; }
    else                  { bz = blockIdx.z; ks = 0; }
    const int Kc = K / KS;

    const unsigned short* pAh = Ah + (long)bz * bsA + (size_t)(m0 + w * 16 + la) * lda + ks * Kc + kg * 8;
    const unsigned short* pAl = Al + (long)bz * bsA + (size_t)(m0 + w * 16 + la) * lda + ks * Kc + kg * 8;
    const unsigned short* pBh = Bh + (long)bz * bsB + (size_t)(n0 + w * 16 + la) * ldb + ks * Kc + kg * 8;
    const unsigned short* pBl = Bl + (long)bz * bsB + (size_t)(n0 + w * 16 + la) * ldb + ks * Kc + kg * 8;

    f32x4 acc[2][2] = {};
    for (int kt = 0; kt < Kc; kt += 32) {
        gload16(pAh, &smem[w * 512]);
        gload16(pAl, &smem[2048 + w * 512]);
        gload16(pBh, &smem[4096 + w * 512]);
        gload16(pBl, &smem[6144 + w * 512]);
        pAh += 32; pAl += 32; pBh += 32; pBl += 32;
        __syncthreads();
        bf16x8 fah[2], fal[2], fbh[2], fbl[2];
#pragma unroll
        for (int i = 0; i < 2; i++) {
            fah[i] = *reinterpret_cast<const bf16x8*>(&smem[(wm * 2 + i) * 512 + lane * 8]);
            fal[i] = *reinterpret_cast<const bf16x8*>(&smem[2048 + (wm * 2 + i) * 512 + lane * 8]);
            fbh[i] = *reinterpret_cast<const bf16x8*>(&smem[4096 + (wn * 2 + i) * 512 + lane * 8]);
            fbl[i] = *reinterpret_cast<const bf16x8*>(&smem[6144 + (wn * 2 + i) * 512 + lane * 8]);
        }
#pragma unroll
        for (int j = 0; j < 2; j++)
#pragma unroll
            for (int i = 0; i < 2; i++) {
                acc[i][j] = __builtin_amdgcn_mfma_f32_16x16x32_bf16(fah[i], fbh[j], acc[i][j], 0, 0, 0);
                acc[i][j] = __builtin_amdgcn_mfma_f32_16x16x32_bf16(fal[i], fbh[j], acc[i][j], 0, 0, 0);
                acc[i][j] = __builtin_amdgcn_mfma_f32_16x16x32_bf16(fah[i], fbl[j], acc[i][j], 0, 0, 0);
            }
        __syncthreads();
    }

    const int r0 = (lane >> 4) * 4, cl = lane & 15;
    if constexpr (KS > 1) {
        const int M = gridDim.y * 64, N = gridDim.x * 64;
        float* Pb = Pf + (long)blockIdx.z * M * N;
#pragma unroll
        for (int i = 0; i < 2; i++)
#pragma unroll
            for (int j = 0; j < 2; j++)
#pragma unroll
                for (int r = 0; r < 4; r++)
                    Pb[(long)(m0 + wm * 32 + i * 16 + r0 + r) * N + (n0 + wn * 32 + j * 16 + cl)]
                        = acc[i][j][r];
    } else {
        float* Cfb = Cf ? Cf + (long)bz * bsC : nullptr;
        unsigned short* Chb = Ch ? Ch + (long)bz * bsC : nullptr;
        unsigned short* Clb = Cl ? Cl + (long)bz * bsC : nullptr;
#pragma unroll
        for (int i = 0; i < 2; i++)
#pragma unroll
            for (int j = 0; j < 2; j++) {
                int gr0 = m0 + wm * 32 + i * 16 + r0;
                int gc  = n0 + wn * 32 + j * 16 + cl;
                float bn = (BMODE == 1) ? bias[gc] : 0.f;
#pragma unroll
                for (int r = 0; r < 4; r++) {
                    int gr = gr0 + r;
                    float v = acc[i][j][r] + bn;
                    if (BMODE == 2 && (gr & 127) == 0) v += 1024.0f * bias[gc];
                    size_t o = (size_t)gr * ldc + gc;
                    if (SPLIT) {
                        unsigned short hh, ll; split2(v, hh, ll);
                        Chb[o] = hh; Clb[o] = ll;
                    } else {
                        Cfb[o] = v;
                    }
                }
            }
    }
}

// ---- split-K reduce + epilogue (float4 grid-stride, pow2 dims via shifts) ---
template<int KS, bool SPLIT>
__global__ void reduce_k(const float* __restrict__ P,
                         float* __restrict__ Cf,
                         unsigned short* __restrict__ Ch, unsigned short* __restrict__ Cl,
                         int mn4bits, int total4)
{
    int e = blockIdx.x * 256 + threadIdx.x;
    if (e >= total4) return;
    int bz = e >> mn4bits, rem = e & ((1 << mn4bits) - 1);
    const float4* P4 = (const float4*)P;
    float4 s = P4[((long)(bz * KS) << mn4bits) + rem];
#pragma unroll
    for (int k = 1; k < KS; k++) {
        float4 t = P4[((long)(bz * KS + k) << mn4bits) + rem];
        s.x += t.x; s.y += t.y; s.z += t.z; s.w += t.w;
    }
    long o4 = ((long)bz << mn4bits) + rem;
    if (SPLIT) {
        ushort4 hh, ll;
        split2(s.x, hh.x, ll.x); split2(s.y, hh.y, ll.y);
        split2(s.z, hh.z, ll.z); split2(s.w, hh.w, ll.w);
        ((ushort4*)Ch)[o4] = hh;
        ((ushort4*)Cl)[o4] = ll;
    } else {
        ((float4*)Cf)[o4] = s;
    }
}

// ---- scores (fp32) + 1024-wide softmax -> attn[bh][64] -----------------------
__global__ void score_k(const float* __restrict__ QF,
                        const float* __restrict__ fq, const float* __restrict__ fk,
                        float* __restrict__ attnW) {
    int bh = blockIdx.x, b = bh >> 4, h = bh & 15;
    const float* QFb = QF + (size_t)b * 393216;     // [128 f2][3072 ch]
    const float* wq = fq + (size_t)h * 4096;
    const float* wk = fk + (size_t)h * 4096;
    __shared__ float red[256];
    int tid = threadIdx.x;
    int f = tid & 63, dg = tid >> 6;
    int cq = h * 64;
    float p = 0.f;
#pragma unroll
    for (int i = 0; i < 16; i++) {
        int d = dg * 16 + i;
        float w2 = wq[f * 64 + d] * wk[f * 64 + d];
        p += w2 * (QFb[(2 * f) * 3072 + cq + d]     * QFb[(2 * f) * 3072 + 1024 + cq + d]
                 + QFb[(2 * f + 1) * 3072 + cq + d] * QFb[(2 * f + 1) * 3072 + 1024 + cq + d]);
    }
    red[tid] = p;
    __syncthreads();
    if (tid < 64) {
        float s = red[tid] + red[tid + 64] + red[tid + 128] + red[tid + 192];
        float mx = s;
        for (int m = 1; m < 64; m <<= 1) mx = fmaxf(mx, __shfl_xor(mx, m));
        mx = fmaxf(mx, 0.0f);                   // padded zero scores join the max
        float e = expf(s - mx);
        float sum = e;
        for (int m = 1; m < 64; m <<= 1) sum += __shfl_xor(sum, m);
        sum += 960.0f * expf(-mx);              // the S-M zero-score entries
        attnW[bh * 64 + tid] = e / sum;
    }
}

// ---- OVW[b][f2][ch] = attn*wv*vf, split hi/lo (float4-wide elementwise) -----
__global__ void ov_k(const float* __restrict__ QF, const float* __restrict__ attnW,
                     const float* __restrict__ fv,
                     unsigned short* __restrict__ OVWh, unsigned short* __restrict__ OVWl) {
    int e = blockIdx.x * 256 + threadIdx.x;     // 131072 float4 = [4][128][1024]
    int b = e >> 15, rem = e & 32767;
    int f2 = rem >> 8, c4 = rem & 255;
    int ch = c4 * 4, h = ch >> 6, d = ch & 63;
    float4 v = *(const float4*)&QF[(size_t)(b * 128 + f2) * 3072 + 2048 + ch];
    float a = attnW[(b * 16 + h) * 64 + (f2 >> 1)];
    const float4 wvv = *(const float4*)&fv[h * 4096 + (f2 >> 1) * 64 + d];
    ushort4 hh, ll;
    split2(a * wvv.x * v.x, hh.x, ll.x);
    split2(a * wvv.y * v.y, hh.y, ll.y);
    split2(a * wvv.z * v.z, hh.z, ll.z);
    split2(a * wvv.w * v.w, hh.w, ll.w);
    long o4 = ((long)(b * 128 + f2) * 1024 + ch) >> 2;
    ((ushort4*)OVWh)[o4] = hh;
    ((ushort4*)OVWl)[o4] = ll;
}

extern "C" void kernel_launch(void* const* d_in, const int* in_sizes, int n_in,
                              void* d_out, int out_size, void* d_ws, size_t ws_size,
                              hipStream_t stream) {
    const float* query  = (const float*)d_in[0];
    const float* w_qkv  = (const float*)d_in[1];
    const float* b_qkv  = (const float*)d_in[2];
    const float* w_out  = (const float*)d_in[3];
    const float* b_out  = (const float*)d_in[4];
    const float* freq_q = (const float*)d_in[5];
    const float* freq_k = (const float*)d_in[6];
    const float* freq_v = (const float*)d_in[7];

    char* W = (char*)d_ws;
    unsigned short* qTh  = (unsigned short*)(W);                  // [4][1024][1024]
    unsigned short* qTl  = (unsigned short*)(W + 8388608);
    unsigned short* Wh   = (unsigned short*)(W + 16777216);       // [3072][1024]
    unsigned short* Wl   = (unsigned short*)(W + 23068672);
    unsigned short* Uh   = (unsigned short*)(W + 29360128);       // [1024][1024]
    unsigned short* Ul   = (unsigned short*)(W + 31457280);
    unsigned short* TWFh = (unsigned short*)(W + 33554432);       // [128][1024]
    unsigned short* TWFl = (unsigned short*)(W + 33816576);
    unsigned short* TWIh = (unsigned short*)(W + 34078720);       // [1024][128]
    unsigned short* TWIl = (unsigned short*)(W + 34340864);
    unsigned short* TWQh = (unsigned short*)(W + 34603008);       // [4][128][1024]
    unsigned short* TWQl = (unsigned short*)(W + 35651584);
    float*          QF   = (float*)        (W + 36700160);        // [512][3072] fp32
    unsigned short* OVWh = (unsigned short*)(W + 42991616);       // [4][128][1024]
    unsigned short* OVWl = (unsigned short*)(W + 44040192);
    unsigned short* POVh = (unsigned short*)(W + 45088768);       // [4][1024][128]
    unsigned short* POVl = (unsigned short*)(W + 46137344);
    float*          attnW= (float*)        (W + 47185920);        // [64][64]
    float*          P_A  = (float*)        (W + 47202304);        // [16][128][1024]
    float*          P_C  = (float*)        (W + 55590912);        // [16][1024][128]
                                                                  // end 63979520 B

    prep<<<5376, 256, 0, stream>>>(query, w_qkv, w_out, qTh, qTl, Wh, Wl, Uh, Ul,
                                   TWFh, TWFl, TWIh, TWIl);

    // A: TWQ[b][f2][k] = sum_s TWF[f2][s]*qT[b][k][s]   (split-K=4 -> partials)
    mfma64<4, 0, false><<<dim3(16, 2, 16), 256, 0, stream>>>(
        TWFh, TWFl, 1024, 0, qTh, qTl, 1024, 1048576,
        nullptr, nullptr, nullptr, 0, 0, P_A, nullptr, 1024);
    reduce_k<4, true><<<512, 256, 0, stream>>>(P_A, nullptr, TWQh, TWQl, 15, 131072);

    // B: QF[(b,f2)][c] = sum_k TWQ[(b,f2)][k]*w_qkv[c][k] (+1024*b_qkv at DC rows)
    mfma64<1, 2, false><<<dim3(48, 8, 1), 256, 0, stream>>>(
        TWQh, TWQl, 1024, 0, Wh, Wl, 1024, 0,
        QF, nullptr, nullptr, 3072, 0, nullptr, b_qkv, 1024);

    // scores -> softmax(1024-wide) -> attn ; then OVW = attn*wv*vf (split)
    score_k<<<64, 256, 0, stream>>>(QF, freq_q, freq_k, attnW);
    ov_k<<<512, 256, 0, stream>>>(QF, attnW, freq_v, OVWh, OVWl);

    // C: POV[b][n][f2] = sum_ch w_out[n][ch]*OVW[b][f2][ch]  (split-K=4)
    mfma64<4, 0, false><<<dim3(2, 16, 16), 256, 0, stream>>>(
        Uh, Ul, 1024, 0, OVWh, OVWl, 1024, 131072,
        nullptr, nullptr, nullptr, 0, 0, P_C, nullptr, 1024);
    reduce_k<4, true><<<512, 256, 0, stream>>>(P_C, nullptr, POVh, POVl, 15, 131072);

    // D: d_out[b][s][n] = sum_f2 TWI[s][f2]*POV[b][n][f2] + b_out[n]
    mfma64<1, 1, false><<<dim3(16, 16, 4), 256, 0, stream>>>(
        TWIh, TWIl, 128, 0, POVh, POVl, 128, 131072,
        (float*)d_out, nullptr, nullptr, 1024, 1048576, nullptr, b_out, 128);
}